// Round 4
// baseline (122.094 us; speedup 1.0000x reference)
//
#include <hip/hip_runtime.h>
#include <stdint.h>

// BiasedFeatureDropout: out = x * mask * 1.25, mask from JAX threefry PRNG
// (partitionable path: bits[i] = o0^o1 of threefry2x32(key=(0,1), (0, i)))
// keep iff bits < T*512, T = 1677722 (bias ch<32) / 6710887 (regular)
// (integer form of u < 0.2f / 0.8f, verified bit-exact in R1/R3)
//
// R4 structure: persistent grid-stride (GRID=3136 -> STRIDE = CHW float4s,
// so channel class is loop-invariant), depth-1 prefetch pipeline, NT loads
// and stores. 8 tiles/thread, last iteration peeled (prefetch would go OOB).

typedef float v4f __attribute__((ext_vector_type(4)));

#define ROTL(x, n) (((x) << (n)) | ((x) >> (32 - (n))))

__device__ __forceinline__ uint32_t threefry_bits(uint32_t i) {
    // key = (0, 1): ks0 = 0, ks1 = 1, ks2 = 0 ^ 1 ^ 0x1BD11BDA = 0x1BD11BDB
    const uint32_t ks0 = 0u, ks1 = 1u, ks2 = 0x1BD11BDBu;
    uint32_t x0 = ks0;          // count_hi = 0
    uint32_t x1 = i + ks1;      // count_lo = i
    // rounds 1-4: rot [13,15,26,6]
    x0 += x1; x1 = ROTL(x1, 13); x1 ^= x0;
    x0 += x1; x1 = ROTL(x1, 15); x1 ^= x0;
    x0 += x1; x1 = ROTL(x1, 26); x1 ^= x0;
    x0 += x1; x1 = ROTL(x1,  6); x1 ^= x0;
    x0 += ks1; x1 += ks2 + 1u;
    // rounds 5-8: rot [17,29,16,24]
    x0 += x1; x1 = ROTL(x1, 17); x1 ^= x0;
    x0 += x1; x1 = ROTL(x1, 29); x1 ^= x0;
    x0 += x1; x1 = ROTL(x1, 16); x1 ^= x0;
    x0 += x1; x1 = ROTL(x1, 24); x1 ^= x0;
    x0 += ks2; x1 += ks0 + 2u;
    // rounds 9-12: rot [13,15,26,6]
    x0 += x1; x1 = ROTL(x1, 13); x1 ^= x0;
    x0 += x1; x1 = ROTL(x1, 15); x1 ^= x0;
    x0 += x1; x1 = ROTL(x1, 26); x1 ^= x0;
    x0 += x1; x1 = ROTL(x1,  6); x1 ^= x0;
    x0 += ks0; x1 += ks1 + 3u;
    // rounds 13-16: rot [17,29,16,24]
    x0 += x1; x1 = ROTL(x1, 17); x1 ^= x0;
    x0 += x1; x1 = ROTL(x1, 29); x1 ^= x0;
    x0 += x1; x1 = ROTL(x1, 16); x1 ^= x0;
    x0 += x1; x1 = ROTL(x1, 24); x1 ^= x0;
    x0 += ks1; x1 += ks2 + 4u;
    // rounds 17-20: rot [13,15,26,6]
    x0 += x1; x1 = ROTL(x1, 13); x1 ^= x0;
    x0 += x1; x1 = ROTL(x1, 15); x1 ^= x0;
    x0 += x1; x1 = ROTL(x1, 26); x1 ^= x0;
    x0 += x1; x1 = ROTL(x1,  6); x1 ^= x0;
    x0 += ks2; x1 += ks0 + 5u;
    return x0 ^ x1;   // partitionable 32-bit path: bits = o0 ^ o1
}

__device__ __forceinline__ void process8(v4f a, v4f b, uint32_t base, uint32_t T,
                                         v4f* oa, v4f* ob) {
    // second float4 sits at element offset 4*half4 = 25690112 = 32*CHW
    // -> same channel class as base
    uint32_t c2 = base + 25690112u;
    uint32_t bitsA[4], bitsB[4];
    #pragma unroll
    for (int k = 0; k < 4; ++k) bitsA[k] = threefry_bits(base + (uint32_t)k);
    #pragma unroll
    for (int k = 0; k < 4; ++k) bitsB[k] = threefry_bits(c2 + (uint32_t)k);
    #pragma unroll
    for (int k = 0; k < 4; ++k) {
        (*oa)[k] = (bitsA[k] < T) ? a[k] * 1.25f : 0.0f;
        (*ob)[k] = (bitsB[k] < T) ? b[k] * 1.25f : 0.0f;
    }
}

__global__ __launch_bounds__(256) void BiasedFeatureDropout_kernel(
        const v4f* __restrict__ x, v4f* __restrict__ out) {
    const uint32_t STRIDE = 802816u;   // float4s advanced per iter = GRID*256
    const uint32_t HALF4  = 6422528u;  // n/8: float4s per half
    uint32_t t = blockIdx.x * 256u + threadIdx.x;   // < 802816 = STRIDE

    // base advance per iter = STRIDE*4 = 4*CHW elements == 0 (mod CHW)
    // -> channel class is loop-invariant; one mod per thread:
    // (t*4) % CHW < BIASE  <=>  t % 200704 < 25088
    uint32_t T = ((t % 200704u) < 25088u) ? (1677722u << 9) : (6710887u << 9);

    v4f a = __builtin_nontemporal_load(&x[t]);
    v4f b = __builtin_nontemporal_load(&x[t + HALF4]);

    #pragma unroll 1
    for (int k = 0; k < 7; ++k) {
        uint32_t tn = t + STRIDE;
        // prefetch next tile; independent of current compute
        v4f an = __builtin_nontemporal_load(&x[tn]);
        v4f bn = __builtin_nontemporal_load(&x[tn + HALF4]);
        v4f oa, ob;
        process8(a, b, t * 4u, T, &oa, &ob);
        __builtin_nontemporal_store(oa, &out[t]);
        __builtin_nontemporal_store(ob, &out[t + HALF4]);
        a = an; b = bn; t = tn;
    }
    // peeled last iteration (no prefetch; would read past input)
    v4f oa, ob;
    process8(a, b, t * 4u, T, &oa, &ob);
    __builtin_nontemporal_store(oa, &out[t]);
    __builtin_nontemporal_store(ob, &out[t + HALF4]);
}

extern "C" void kernel_launch(void* const* d_in, const int* in_sizes, int n_in,
                              void* d_out, int out_size, void* d_ws, size_t ws_size,
                              hipStream_t stream) {
    const float* x = (const float*)d_in[0];
    float* out = (float*)d_out;
    // n = 51,380,224; half4 = 6,422,528 = 8 * (3136*256) exactly
    int block = 256;
    int grid = 3136;
    BiasedFeatureDropout_kernel<<<grid, block, 0, stream>>>(
        (const v4f*)x, (v4f*)out);
}

// Round 5
// 94.635 us; speedup vs baseline: 1.2901x; 1.2901x over previous
//
#include <hip/hip_runtime.h>
#include <stdint.h>

// BiasedFeatureDropout: out = x * mask * 1.25, mask from JAX threefry PRNG
// (partitionable path: bits[i] = o0^o1 of threefry2x32(key=(0,1), (0, i)))
// keep iff bits < T*512, T = 1677722 (bias ch<32) / 6710887 (regular)
// (integer form of u < 0.2f / 0.8f, verified bit-exact R1/R3/R4)
//
// R5: revert to R3 one-shot structure (R4 persistent loop regressed);
// force rotates to single v_alignbit_b32 via __builtin_amdgcn_alignbit
// (R4 profile: VALUBusy 85% -> suspected 3-op rotate codegen).

typedef float v4f __attribute__((ext_vector_type(4)));

// rotl(x,n) = alignbit(x, x, 32-n): ({x,x} >> (32-n))[31:0] = (x<<n)|(x>>(32-n))
#define ROTL(x, n) __builtin_amdgcn_alignbit((x), (x), 32 - (n))

__device__ __forceinline__ uint32_t threefry_bits(uint32_t i) {
    // key = (0, 1): ks0 = 0, ks1 = 1, ks2 = 0 ^ 1 ^ 0x1BD11BDA = 0x1BD11BDB
    const uint32_t ks0 = 0u, ks1 = 1u, ks2 = 0x1BD11BDBu;
    uint32_t x0 = ks0;          // count_hi = 0
    uint32_t x1 = i + ks1;      // count_lo = i
    // rounds 1-4: rot [13,15,26,6]
    x0 += x1; x1 = ROTL(x1, 13); x1 ^= x0;
    x0 += x1; x1 = ROTL(x1, 15); x1 ^= x0;
    x0 += x1; x1 = ROTL(x1, 26); x1 ^= x0;
    x0 += x1; x1 = ROTL(x1,  6); x1 ^= x0;
    x0 += ks1; x1 += ks2 + 1u;
    // rounds 5-8: rot [17,29,16,24]
    x0 += x1; x1 = ROTL(x1, 17); x1 ^= x0;
    x0 += x1; x1 = ROTL(x1, 29); x1 ^= x0;
    x0 += x1; x1 = ROTL(x1, 16); x1 ^= x0;
    x0 += x1; x1 = ROTL(x1, 24); x1 ^= x0;
    x0 += ks2; x1 += ks0 + 2u;
    // rounds 9-12: rot [13,15,26,6]
    x0 += x1; x1 = ROTL(x1, 13); x1 ^= x0;
    x0 += x1; x1 = ROTL(x1, 15); x1 ^= x0;
    x0 += x1; x1 = ROTL(x1, 26); x1 ^= x0;
    x0 += x1; x1 = ROTL(x1,  6); x1 ^= x0;
    x0 += ks0; x1 += ks1 + 3u;
    // rounds 13-16: rot [17,29,16,24]
    x0 += x1; x1 = ROTL(x1, 17); x1 ^= x0;
    x0 += x1; x1 = ROTL(x1, 29); x1 ^= x0;
    x0 += x1; x1 = ROTL(x1, 16); x1 ^= x0;
    x0 += x1; x1 = ROTL(x1, 24); x1 ^= x0;
    x0 += ks1; x1 += ks2 + 4u;
    // rounds 17-20: rot [13,15,26,6]
    x0 += x1; x1 = ROTL(x1, 13); x1 ^= x0;
    x0 += x1; x1 = ROTL(x1, 15); x1 ^= x0;
    x0 += x1; x1 = ROTL(x1, 26); x1 ^= x0;
    x0 += x1; x1 = ROTL(x1,  6); x1 ^= x0;
    x0 += ks2; x1 += ks0 + 5u;
    return x0 ^ x1;   // partitionable 32-bit path: bits = o0 ^ o1
}

__global__ __launch_bounds__(256) void BiasedFeatureDropout_kernel(
        const v4f* __restrict__ x, v4f* __restrict__ out, uint32_t half4) {
    uint32_t t = blockIdx.x * 256u + threadIdx.x;
    if (t >= half4) return;

    const uint32_t CHW   = 802816u;   // 256*56*56
    const uint32_t BIASE = 100352u;   // 32*56*56

    uint32_t base = t * 4u;
    // second float4 sits at element offset half4*4 = 25690112 = 32*CHW
    // -> same remainder mod CHW -> same channel class -> ONE threshold
    uint32_t rem = base % CHW;
    uint32_t T = (rem < BIASE) ? (1677722u << 9) : (6710887u << 9);

    // issue both loads up front; threefry depends only on the index,
    // so the integer compute overlaps the HBM latency
    v4f a = x[t];
    v4f b = x[t + half4];
    uint32_t c2 = base + half4 * 4u;

    uint32_t bitsA[4], bitsB[4];
    #pragma unroll
    for (int k = 0; k < 4; ++k) bitsA[k] = threefry_bits(base + (uint32_t)k);
    #pragma unroll
    for (int k = 0; k < 4; ++k) bitsB[k] = threefry_bits(c2 + (uint32_t)k);

    v4f oa, ob;
    #pragma unroll
    for (int k = 0; k < 4; ++k) {
        oa[k] = (bitsA[k] < T) ? a[k] * 1.25f : 0.0f;
        ob[k] = (bitsB[k] < T) ? b[k] * 1.25f : 0.0f;
    }
    __builtin_nontemporal_store(oa, &out[t]);
    __builtin_nontemporal_store(ob, &out[t + half4]);
}

extern "C" void kernel_launch(void* const* d_in, const int* in_sizes, int n_in,
                              void* d_out, int out_size, void* d_ws, size_t ws_size,
                              hipStream_t stream) {
    const float* x = (const float*)d_in[0];
    float* out = (float*)d_out;
    uint32_t n = (uint32_t)out_size;   // 51,380,224
    uint32_t half4 = n / 8u;           // 6,422,528 float4s per half
    int block = 256;
    int grid = (int)((half4 + block - 1) / block);   // 25088
    BiasedFeatureDropout_kernel<<<grid, block, 0, stream>>>(
        (const v4f*)x, (v4f*)out, half4);
}

// Round 6
// 94.500 us; speedup vs baseline: 1.2920x; 1.0014x over previous
//
#include <hip/hip_runtime.h>
#include <stdint.h>

// BiasedFeatureDropout: out = x * mask * 1.25, mask from JAX threefry PRNG
// (partitionable path: bits[i] = o0^o1 of threefry2x32(key=(0,1), (0, i)))
// keep iff bits < T*512, T = 1677722 (bias ch<32) / 6710887 (regular)
// (integer form of u < 0.2f / 0.8f, verified bit-exact R1-R5)
//
// R6: 16 elems/thread via 4 streams at quarter offsets (quarter = 16*CHW
// -> one channel test per thread). 4 loads in flight per wave (2x MLP of
// R3), per-thread fixed costs amortized 2x. R5 lesson: rotates already
// compile to v_alignbit_b32; VALUBusy on gfx950 is ~2x inflated (gfx94x
// SIMD-16 formula); kernel is latency/overhead-bound, not VALU-bound.

typedef float v4f __attribute__((ext_vector_type(4)));

#define ROTL(x, n) __builtin_amdgcn_alignbit((x), (x), 32 - (n))

__device__ __forceinline__ uint32_t threefry_bits(uint32_t i) {
    // key = (0, 1): ks0 = 0, ks1 = 1, ks2 = 0 ^ 1 ^ 0x1BD11BDA = 0x1BD11BDB
    const uint32_t ks0 = 0u, ks1 = 1u, ks2 = 0x1BD11BDBu;
    uint32_t x0 = ks0;          // count_hi = 0
    uint32_t x1 = i + ks1;      // count_lo = i
    // rounds 1-4: rot [13,15,26,6]
    x0 += x1; x1 = ROTL(x1, 13); x1 ^= x0;
    x0 += x1; x1 = ROTL(x1, 15); x1 ^= x0;
    x0 += x1; x1 = ROTL(x1, 26); x1 ^= x0;
    x0 += x1; x1 = ROTL(x1,  6); x1 ^= x0;
    x0 += ks1; x1 += ks2 + 1u;
    // rounds 5-8: rot [17,29,16,24]
    x0 += x1; x1 = ROTL(x1, 17); x1 ^= x0;
    x0 += x1; x1 = ROTL(x1, 29); x1 ^= x0;
    x0 += x1; x1 = ROTL(x1, 16); x1 ^= x0;
    x0 += x1; x1 = ROTL(x1, 24); x1 ^= x0;
    x0 += ks2; x1 += ks0 + 2u;
    // rounds 9-12: rot [13,15,26,6]
    x0 += x1; x1 = ROTL(x1, 13); x1 ^= x0;
    x0 += x1; x1 = ROTL(x1, 15); x1 ^= x0;
    x0 += x1; x1 = ROTL(x1, 26); x1 ^= x0;
    x0 += x1; x1 = ROTL(x1,  6); x1 ^= x0;
    x0 += ks0; x1 += ks1 + 3u;
    // rounds 13-16: rot [17,29,16,24]
    x0 += x1; x1 = ROTL(x1, 17); x1 ^= x0;
    x0 += x1; x1 = ROTL(x1, 29); x1 ^= x0;
    x0 += x1; x1 = ROTL(x1, 16); x1 ^= x0;
    x0 += x1; x1 = ROTL(x1, 24); x1 ^= x0;
    x0 += ks1; x1 += ks2 + 4u;
    // rounds 17-20: rot [13,15,26,6]
    x0 += x1; x1 = ROTL(x1, 13); x1 ^= x0;
    x0 += x1; x1 = ROTL(x1, 15); x1 ^= x0;
    x0 += x1; x1 = ROTL(x1, 26); x1 ^= x0;
    x0 += x1; x1 = ROTL(x1,  6); x1 ^= x0;
    x0 += ks2; x1 += ks0 + 5u;
    return x0 ^ x1;   // partitionable 32-bit path: bits = o0 ^ o1
}

__global__ __launch_bounds__(256) void BiasedFeatureDropout_kernel(
        const v4f* __restrict__ x, v4f* __restrict__ out) {
    const uint32_t Q4 = 3211264u;     // float4s per quarter = n/16
    const uint32_t QE = 12845056u;    // elems per quarter = 16*CHW
    uint32_t t = blockIdx.x * 256u + threadIdx.x;   // < Q4

    uint32_t base = t * 4u;
    // quarter offset QE == 0 (mod CHW) -> all 4 streams share channel class
    uint32_t T = ((base % 802816u) < 100352u) ? (1677722u << 9)
                                              : (6710887u << 9);

    // 4 independent loads in flight; threefry work (~1150 insts) hides them
    v4f d0 = x[t];
    v4f d1 = x[t + Q4];
    v4f d2 = x[t + 2u * Q4];
    v4f d3 = x[t + 3u * Q4];

    uint32_t bits[16];
    #pragma unroll
    for (int s = 0; s < 4; ++s) {
        uint32_t c = base + (uint32_t)s * QE;
        #pragma unroll
        for (int k = 0; k < 4; ++k)
            bits[s * 4 + k] = threefry_bits(c + (uint32_t)k);
    }

    v4f o0, o1, o2, o3;
    #pragma unroll
    for (int k = 0; k < 4; ++k) {
        o0[k] = (bits[k]      < T) ? d0[k] * 1.25f : 0.0f;
        o1[k] = (bits[4 + k]  < T) ? d1[k] * 1.25f : 0.0f;
        o2[k] = (bits[8 + k]  < T) ? d2[k] * 1.25f : 0.0f;
        o3[k] = (bits[12 + k] < T) ? d3[k] * 1.25f : 0.0f;
    }
    __builtin_nontemporal_store(o0, &out[t]);
    __builtin_nontemporal_store(o1, &out[t + Q4]);
    __builtin_nontemporal_store(o2, &out[t + 2u * Q4]);
    __builtin_nontemporal_store(o3, &out[t + 3u * Q4]);
}

extern "C" void kernel_launch(void* const* d_in, const int* in_sizes, int n_in,
                              void* d_out, int out_size, void* d_ws, size_t ws_size,
                              hipStream_t stream) {
    const float* x = (const float*)d_in[0];
    float* out = (float*)d_out;
    // n = 51,380,224 = 16 * 3,211,264; blocks = 3,211,264/256 = 12,544 exact
    int block = 256;
    int grid = 12544;
    BiasedFeatureDropout_kernel<<<grid, block, 0, stream>>>(
        (const v4f*)x, (v4f*)out);
}

// Round 7
// 94.389 us; speedup vs baseline: 1.2935x; 1.0012x over previous
//
#include <hip/hip_runtime.h>
#include <stdint.h>

// BiasedFeatureDropout: out = x * mask * 1.25, mask from JAX threefry PRNG
// (partitionable path: bits[i] = o0^o1 of threefry2x32(key=(0,1), (0, i)))
// keep iff bits < T*512, T = 1677722 (bias ch<32) / 6710887 (regular)
// (integer form of u < 0.2f / 0.8f, verified bit-exact R1-R6)
//
// R7: VALU-bound (R3=R5=R6 pinned at 94.5us). Hand-minimized threefry for
// key=(0,1): round-1 add vs x0=0 elided (rename), injection-3 x0+=ks0=0
// elided, 4 remaining x0-injections written as x0+x1+c to force v_add3_u32.
// Target ~66 ops/elem vs ~76. Structure identical to R6 for clean A/B.

typedef float v4f __attribute__((ext_vector_type(4)));

#define ROTL(x, n) __builtin_amdgcn_alignbit((x), (x), 32 - (n))

__device__ __forceinline__ uint32_t threefry_bits(uint32_t i) {
    const uint32_t KS2 = 0x1BD11BDBu;   // 0 ^ 1 ^ 0x1BD11BDA
    // x0 = hi + ks0 = 0; x1 = lo + ks1 = i + 1
    uint32_t x1 = i + 1u;
    // round 1: x0 += x1 (x0 was 0 -> rename); x1 = rotl(x1,13) ^ x0
    uint32_t x0 = x1;
    x1 = ROTL(x1, 13) ^ x0;
    x0 += x1; x1 = ROTL(x1, 15) ^ x0;   // round 2
    x0 += x1; x1 = ROTL(x1, 26) ^ x0;   // round 3
    x0 += x1; x1 = ROTL(x1,  6) ^ x0;   // round 4
    // inj1: x0 += ks1(=1); x1 += ks2+1  (x0-add fused into round-5 add)
    x1 += KS2 + 1u;
    x0 = x0 + x1 + 1u;                  // v_add3
    x1 = ROTL(x1, 17) ^ x0;             // round 5
    x0 += x1; x1 = ROTL(x1, 29) ^ x0;   // round 6
    x0 += x1; x1 = ROTL(x1, 16) ^ x0;   // round 7
    x0 += x1; x1 = ROTL(x1, 24) ^ x0;   // round 8
    // inj2: x0 += ks2; x1 += ks0+2 = 2
    x1 += 2u;
    x0 = x0 + x1 + KS2;                 // v_add3
    x1 = ROTL(x1, 13) ^ x0;             // round 9
    x0 += x1; x1 = ROTL(x1, 15) ^ x0;   // round 10
    x0 += x1; x1 = ROTL(x1, 26) ^ x0;   // round 11
    x0 += x1; x1 = ROTL(x1,  6) ^ x0;   // round 12
    // inj3: x0 += ks0 = 0 (FREE); x1 += ks1+3 = 4
    x1 += 4u;
    x0 += x1;                           // round-13 add only
    x1 = ROTL(x1, 17) ^ x0;             // round 13
    x0 += x1; x1 = ROTL(x1, 29) ^ x0;   // round 14
    x0 += x1; x1 = ROTL(x1, 16) ^ x0;   // round 15
    x0 += x1; x1 = ROTL(x1, 24) ^ x0;   // round 16
    // inj4: x0 += ks1 = 1; x1 += ks2+4
    x1 += KS2 + 4u;
    x0 = x0 + x1 + 1u;                  // v_add3
    x1 = ROTL(x1, 13) ^ x0;             // round 17
    x0 += x1; x1 = ROTL(x1, 15) ^ x0;   // round 18
    x0 += x1; x1 = ROTL(x1, 26) ^ x0;   // round 19
    x0 += x1; x1 = ROTL(x1,  6) ^ x0;   // round 20
    // inj5: x0 += ks2; x1 += ks0+5 = 5; output = x0 ^ x1
    return (x0 + KS2) ^ (x1 + 5u);
}

__global__ __launch_bounds__(256) void BiasedFeatureDropout_kernel(
        const v4f* __restrict__ x, v4f* __restrict__ out) {
    const uint32_t Q4 = 3211264u;     // float4s per quarter = n/16
    const uint32_t QE = 12845056u;    // elems per quarter = 16*CHW
    uint32_t t = blockIdx.x * 256u + threadIdx.x;   // < Q4

    uint32_t base = t * 4u;
    // quarter offset QE == 0 (mod CHW) -> all 4 streams share channel class
    uint32_t T = ((base % 802816u) < 100352u) ? (1677722u << 9)
                                              : (6710887u << 9);

    v4f d0 = x[t];
    v4f d1 = x[t + Q4];
    v4f d2 = x[t + 2u * Q4];
    v4f d3 = x[t + 3u * Q4];

    uint32_t bits[16];
    #pragma unroll
    for (int s = 0; s < 4; ++s) {
        uint32_t c = base + (uint32_t)s * QE;
        #pragma unroll
        for (int k = 0; k < 4; ++k)
            bits[s * 4 + k] = threefry_bits(c + (uint32_t)k);
    }

    v4f o0, o1, o2, o3;
    #pragma unroll
    for (int k = 0; k < 4; ++k) {
        o0[k] = (bits[k]      < T) ? d0[k] * 1.25f : 0.0f;
        o1[k] = (bits[4 + k]  < T) ? d1[k] * 1.25f : 0.0f;
        o2[k] = (bits[8 + k]  < T) ? d2[k] * 1.25f : 0.0f;
        o3[k] = (bits[12 + k] < T) ? d3[k] * 1.25f : 0.0f;
    }
    __builtin_nontemporal_store(o0, &out[t]);
    __builtin_nontemporal_store(o1, &out[t + Q4]);
    __builtin_nontemporal_store(o2, &out[t + 2u * Q4]);
    __builtin_nontemporal_store(o3, &out[t + 3u * Q4]);
}

extern "C" void kernel_launch(void* const* d_in, const int* in_sizes, int n_in,
                              void* d_out, int out_size, void* d_ws, size_t ws_size,
                              hipStream_t stream) {
    const float* x = (const float*)d_in[0];
    float* out = (float*)d_out;
    // n = 51,380,224 = 16 * 3,211,264; blocks = 3,211,264/256 = 12,544 exact
    int block = 256;
    int grid = 12544;
    BiasedFeatureDropout_kernel<<<grid, block, 0, stream>>>(
        (const v4f*)x, (v4f*)out);
}